// Round 18
// baseline (174.779 us; speedup 1.0000x reference)
//
#include <hip/hip_runtime.h>
#include <hip/hip_bf16.h>

typedef __bf16 bf16x8 __attribute__((ext_vector_type(8)));
typedef float f32x4 __attribute__((ext_vector_type(4)));
typedef float f32x16 __attribute__((ext_vector_type(16)));
typedef unsigned int uint2v __attribute__((ext_vector_type(2)));

#define LOG2E 1.44269504088896340736f

static __device__ __forceinline__ unsigned int cvtpk_bf16(float lo, float hi) {
  unsigned int r;
  asm("v_cvt_pk_bf16_f32 %0, %1, %2" : "=v"(r) : "v"(lo), "v"(hi));
  return r;
}

// All three weight transposes in one launch.
__global__ __launch_bounds__(256) void prep_k(
    const float* __restrict__ Wq, const float* __restrict__ Wkv,
    const float* __restrict__ Wo, __bf16* __restrict__ WqT,
    __bf16* __restrict__ WkvT, __bf16* __restrict__ WoT) {
  int id = blockIdx.x;
  const float* in;
  __bf16* out;
  int R, C, bx, by;
  float scale;
  if (id < 256) {
    in = Wq; out = WqT; R = 512; C = 512; scale = 0.125f;
    bx = id & 15; by = id >> 4;
  } else if (id < 768) {
    int i2 = id - 256;
    in = Wkv; out = WkvT; R = 512; C = 1024; scale = 1.0f;
    bx = i2 & 31; by = i2 >> 5;
  } else {
    int i2 = id - 768;
    in = Wo; out = WoT; R = 512; C = 512; scale = 1.0f;
    bx = i2 & 15; by = i2 >> 4;
  }
  __shared__ float tile[32][33];
  int c0 = bx * 32, r0 = by * 32;
  int tx = threadIdx.x & 31, ty = threadIdx.x >> 5;
  for (int i = ty; i < 32; i += 8)
    tile[i][tx] = in[(size_t)(r0 + i) * C + c0 + tx];
  __syncthreads();
  for (int i = ty; i < 32; i += 8)
    out[(size_t)(c0 + i) * R + r0 + tx] = (__bf16)(tile[tx][i] * scale);
}

// Streamed GEMM: C[128m x 64n] = A[M][512] @ Bt[N][512]^T per block.
// B (weights, 64x512 = 64KB) staged to LDS ONCE (one barrier, fragment-
// granule, conflict-free). A-fragments load DIRECTLY from global into TWO
// NAMED register sets with distance-1 prefetch: chunk c+1's loads issue
// before chunk c's compute -> compiler emits counted vmcnt per set, one
// full chunk of latency cover, 8 free-running waves/CU add TLP. No Al, no
// K-loop barriers: LDS pipe (the r15 bottleneck, ~72% busy) drops ~4x.
// (r16 failed because its A loads had ZERO prefetch distance.)
// EPI 0: q scatter; EPI 1: gx<8 k scatter, gx>=8 one-head vT transpose;
// EPI 2: fp32 row-major [M][512].
template <int EPI, bool AF32>
static __device__ __forceinline__ void gemm_body(
    char* smem, const void* __restrict__ Aptr, const __bf16* __restrict__ Bt,
    void* __restrict__ outp, void* __restrict__ outp2, int id) {
  constexpr int K = 512;
  __bf16* Bl = (__bf16*)smem;  // 64 granules x 64 lanes x 16B = 64KB (all K)
  const int t = threadIdx.x, lane = t & 63, wid = t >> 6;
  const int lrow = lane & 15, lgrp = lane >> 4;
  const int gy = id & 63, gx = id >> 6;
  const int m0 = gy * 128, n0 = gx * 64;
  const int wr = (wid >> 1) * 64, wc = (wid & 1) * 32;

  // stage B once: granule g = j*4 + wid holds B[n0+(g>>4)*16+lrow]
  // [(g&15)*32 + lgrp*8 ..+7] at byte g*1024 + lane*16 (r16 mapping, proven).
#pragma unroll
  for (int j = 0; j < 16; ++j) {
    const int g = j * 4 + wid;
    bf16x8 v = *(const bf16x8*)&Bt[(size_t)(n0 + (g >> 4) * 16 + lrow) * K +
                                   (g & 15) * 32 + lgrp * 8];
    *(bf16x8*)((char*)Bl + g * 1024 + lane * 16) = v;
  }

  // per-mi A base pointers (A-frag row = m0+wr+mi*16+lrow, k = c*32+lgrp*8)
  const float* aPf[4];
  const __bf16* aPh[4];
#pragma unroll
  for (int mi = 0; mi < 4; ++mi) {
    size_t off = (size_t)(m0 + wr + mi * 16 + lrow) * K + lgrp * 8;
    if constexpr (AF32) aPf[mi] = (const float*)Aptr + off;
    else aPh[mi] = (const __bf16*)Aptr + off;
  }

  __syncthreads();  // B resident; only barrier before epilogue

  f32x4 acc[4][2] = {};
  const int bq = wc >> 4;  // 0 or 2

  // two NAMED A register sets (rule #20): raw loads, convert at use
  float4 sAf[4][2], sBf[4][2];
  bf16x8 sAh[4], sBh[4];

  auto loadA_A = [&](int c) {
#pragma unroll
    for (int mi = 0; mi < 4; ++mi) {
      if constexpr (AF32) {
        sAf[mi][0] = *(const float4*)(aPf[mi] + c * 32);
        sAf[mi][1] = *(const float4*)(aPf[mi] + c * 32 + 4);
      } else {
        sAh[mi] = *(const bf16x8*)(aPh[mi] + c * 32);
      }
    }
  };
  auto loadA_B = [&](int c) {
#pragma unroll
    for (int mi = 0; mi < 4; ++mi) {
      if constexpr (AF32) {
        sBf[mi][0] = *(const float4*)(aPf[mi] + c * 32);
        sBf[mi][1] = *(const float4*)(aPf[mi] + c * 32 + 4);
      } else {
        sBh[mi] = *(const bf16x8*)(aPh[mi] + c * 32);
      }
    }
  };
  auto computeA = [&](int c) {
    bf16x8 af[4];
#pragma unroll
    for (int mi = 0; mi < 4; ++mi) {
      if constexpr (AF32) {
        float4 f0 = sAf[mi][0], f1 = sAf[mi][1];
        bf16x8 h = {(__bf16)f0.x, (__bf16)f0.y, (__bf16)f0.z, (__bf16)f0.w,
                    (__bf16)f1.x, (__bf16)f1.y, (__bf16)f1.z, (__bf16)f1.w};
        af[mi] = h;
      } else {
        af[mi] = sAh[mi];
      }
    }
    __builtin_amdgcn_s_setprio(1);
#pragma unroll
    for (int ni = 0; ni < 2; ++ni) {
      bf16x8 bfr = *(const bf16x8*)((char*)Bl +
                                    ((bq + ni) * 16 + c) * 1024 + lane * 16);
#pragma unroll
      for (int mi = 0; mi < 4; ++mi)
        acc[mi][ni] = __builtin_amdgcn_mfma_f32_16x16x32_bf16(
            af[mi], bfr, acc[mi][ni], 0, 0, 0);
    }
    __builtin_amdgcn_s_setprio(0);
  };
  auto computeB = [&](int c) {
    bf16x8 af[4];
#pragma unroll
    for (int mi = 0; mi < 4; ++mi) {
      if constexpr (AF32) {
        float4 f0 = sBf[mi][0], f1 = sBf[mi][1];
        bf16x8 h = {(__bf16)f0.x, (__bf16)f0.y, (__bf16)f0.z, (__bf16)f0.w,
                    (__bf16)f1.x, (__bf16)f1.y, (__bf16)f1.z, (__bf16)f1.w};
        af[mi] = h;
      } else {
        af[mi] = sBh[mi];
      }
    }
    __builtin_amdgcn_s_setprio(1);
#pragma unroll
    for (int ni = 0; ni < 2; ++ni) {
      bf16x8 bfr = *(const bf16x8*)((char*)Bl +
                                    ((bq + ni) * 16 + c) * 1024 + lane * 16);
#pragma unroll
      for (int mi = 0; mi < 4; ++mi)
        acc[mi][ni] = __builtin_amdgcn_mfma_f32_16x16x32_bf16(
            af[mi], bfr, acc[mi][ni], 0, 0, 0);
    }
    __builtin_amdgcn_s_setprio(0);
  };

  // 16 chunks of k=32, distance-1 register pipeline (clamped over-read ok)
  loadA_A(0);
#pragma unroll
  for (int c2 = 0; c2 < 16; c2 += 2) {
    loadA_B(c2 + 1);
    computeA(c2);
    loadA_A((c2 + 2) & 15);
    computeB(c2 + 1);
  }

  if (EPI == 1 && n0 >= 512) {
    // one v head (hglob = gx-8): transpose 64hd x 128m through Bl scratch
    __syncthreads();  // all waves done reading Bl
    __bf16* scratch = Bl;  // [64][128] = 16KB
#pragma unroll
    for (int mi = 0; mi < 4; ++mi)
#pragma unroll
      for (int ni = 0; ni < 2; ++ni)
#pragma unroll
        for (int i = 0; i < 4; ++i)
          scratch[(wc + ni * 16 + lrow) * 128 + wr + mi * 16 + lgrp * 4 + i] =
              (__bf16)acc[mi][ni][i];
    __syncthreads();
    const int b = m0 >> 11, mloc = m0 & 2047, hglob = gx - 8;
    int hd = t >> 2, ms = (t & 3) * 32;
    __bf16* dst = (__bf16*)outp2 +
                  ((size_t)(b * 8 + hglob) * 64 + hd) * 2048 + mloc + ms;
    const __bf16* srcT = scratch + hd * 128 + ms;
#pragma unroll
    for (int c2 = 0; c2 < 32; c2 += 8)
      *(bf16x8*)&dst[c2] = *(const bf16x8*)&srcT[c2];
    return;
  }

#pragma unroll
  for (int mi = 0; mi < 4; ++mi)
#pragma unroll
    for (int ni = 0; ni < 2; ++ni)
#pragma unroll
      for (int i = 0; i < 4; ++i) {
        int r = m0 + wr + mi * 16 + lgrp * 4 + i;
        int c = n0 + wc + ni * 16 + lrow;
        float v = acc[mi][ni][i];
        if (EPI == 0) {
          int b = r >> 11, n = r & 2047, h = c >> 6, hd = c & 63;
          ((__bf16*)outp)[((size_t)(b * 8 + h) * 2048 + n) * 64 + hd] = (__bf16)v;
        } else if (EPI == 1) {
          int b = r >> 11, m = r & 2047, h = c >> 6, hd = c & 63;
          ((__bf16*)outp)[((size_t)(b * 8 + h) * 2048 + m) * 64 + hd] = (__bf16)v;
        } else {
          ((float*)outp)[(size_t)r * 512 + c] = v;
        }
      }
}

// Fused QKV projection: blocks [0,1024) = ctx->k,vT (EPI1, N=1024);
// blocks [1024,1536) = x->q (EPI0, N=512). One 64KB B-LDS each.
__global__ __launch_bounds__(256, 2) void qkv_k(
    const float* __restrict__ ctx, const __bf16* __restrict__ WkvT,
    void* __restrict__ kb, void* __restrict__ vtb,
    const float* __restrict__ x, const __bf16* __restrict__ WqT,
    void* __restrict__ qb) {
  __shared__ __attribute__((aligned(16))) char smem[64 * 1024];
  int id = blockIdx.x;
  if (id < 1024)
    gemm_body<1, true>(smem, ctx, WkvT, kb, vtb, id);
  else
    gemm_body<0, true>(smem, x, WqT, qb, nullptr, id - 1024);
}

// Output projection: aob (bf16) @ WoT -> fp32 out. 512 blocks.
__global__ __launch_bounds__(256, 2) void gemm2_k(
    const __bf16* __restrict__ A, const __bf16* __restrict__ Bt,
    float* __restrict__ out) {
  __shared__ __attribute__((aligned(16))) char smem[64 * 1024];
  gemm_body<2, false>(smem, A, Bt, out, nullptr, blockIdx.x);
}

// Flash attention (round-13 version, measured 53.5us): 32x32x16 MFMA,
// in-register P, fixed-shift softmax, KVBLK=128 (16 phases), fragment-
// granule LDS, 2-phase dbuf, reg-staged, unconditional staging.
__global__ __launch_bounds__(256, 2) void attn_k(
    const __bf16* __restrict__ q, const __bf16* __restrict__ k,
    const __bf16* __restrict__ vt, __bf16* __restrict__ ao) {
  const int id = blockIdx.x;
  const int bh = id & 31;  // id%8 == bh%8 -> one bh's blocks share an XCD
  const int q0 = (id >> 5) * 128;
  const int t = threadIdx.x, wid = t >> 6, lane = t & 63;
  const int l31 = lane & 31, hi = lane >> 5;

  __shared__ __attribute__((aligned(16))) __bf16 kl[2][8192];  // 128m x 64hd
  __shared__ __attribute__((aligned(16))) __bf16 vl[2][8192];  // 64hd x 128m

  const size_t qrow = (size_t)bh * 2048 + q0 + wid * 32 + l31;
  bf16x8 qf[4];
#pragma unroll
  for (int kc = 0; kc < 4; ++kc)
    qf[kc] = *(const bf16x8*)&q[qrow * 64 + kc * 16 + hi * 8];

  const __bf16* kp = k + (size_t)bh * 2048 * 64 + (size_t)l31 * 64 + wid * 16 + hi * 8;
  const __bf16* vp = vt + (size_t)bh * 64 * 2048 + (size_t)l31 * 2048 + wid * 16 + hi * 8;
  const int sg = wid * 1024 + lane * 16;  // LDS byte base, +j*4096

  bf16x8 ones;
#pragma unroll
  for (int e = 0; e < 8; ++e) ones[e] = (__bf16)1.0f;

  f32x16 oacc[2] = {};
  f32x16 lacc = {};
  const float ncl = -8.0f * LOG2E;

  bf16x8 kr[4], vr[4];
  auto loadKV = [&]() {
    kr[0] = *(const bf16x8*)kp;
    kr[1] = *(const bf16x8*)(kp + 2048);
    kr[2] = *(const bf16x8*)(kp + 4096);
    kr[3] = *(const bf16x8*)(kp + 6144);
    vr[0] = *(const bf16x8*)vp;
    vr[1] = *(const bf16x8*)(vp + 64);
    vr[2] = *(const bf16x8*)(vp + 65536);
    vr[3] = *(const bf16x8*)(vp + 65600);
    kp += 8192;
    vp += 128;
  };
  auto storeKV = [&](int bf) {
#pragma unroll
    for (int j = 0; j < 4; ++j) {
      *(bf16x8*)((char*)kl[bf] + sg + j * 4096) = kr[j];
      *(bf16x8*)((char*)vl[bf] + sg + j * 4096) = vr[j];
    }
  };
  auto computeTile = [&](int bf) {
    f32x16 sacc[4] = {};
    __builtin_amdgcn_s_setprio(1);
#pragma unroll
    for (int kc = 0; kc < 4; ++kc)
#pragma unroll
      for (int mc = 0; mc < 4; ++mc) {
        bf16x8 ak = *(const bf16x8*)((char*)kl[bf] + (mc * 4 + kc) * 1024 + lane * 16);
        sacc[mc] = __builtin_amdgcn_mfma_f32_32x32x16_bf16(ak, qf[kc], sacc[mc], 0, 0, 0);
      }
    __builtin_amdgcn_s_setprio(0);

#pragma unroll
    for (int mc = 0; mc < 4; ++mc)
#pragma unroll
      for (int r = 0; r < 16; ++r)
        sacc[mc][r] =
            __builtin_amdgcn_exp2f(__builtin_fmaf(sacc[mc][r], LOG2E, ncl));

    bf16x8 paf[8];
#pragma unroll
    for (int mc = 0; mc < 4; ++mc)
#pragma unroll
      for (int w = 0; w < 2; ++w) {
        int b0 = w * 8;
        unsigned int dwA = cvtpk_bf16(sacc[mc][b0 + 0], sacc[mc][b0 + 1]);
        unsigned int dwB = cvtpk_bf16(sacc[mc][b0 + 2], sacc[mc][b0 + 3]);
        unsigned int dwC = cvtpk_bf16(sacc[mc][b0 + 4], sacc[mc][b0 + 5]);
        unsigned int dwD = cvtpk_bf16(sacc[mc][b0 + 6], sacc[mc][b0 + 7]);
        uint2v r0 = __builtin_amdgcn_permlane32_swap(dwA, dwC, false, false);
        uint2v r1 = __builtin_amdgcn_permlane32_swap(dwB, dwD, false, false);
        union { unsigned int u[4]; bf16x8 v; } f;
        f.u[0] = r0[0];
        f.u[1] = r1[0];
        f.u[2] = r0[1];
        f.u[3] = r1[1];
        paf[mc * 2 + w] = f.v;
      }

    __builtin_amdgcn_s_setprio(1);
#pragma unroll
    for (int mk = 0; mk < 8; ++mk) {
#pragma unroll
      for (int nc = 0; nc < 2; ++nc) {
        bf16x8 vf = *(const bf16x8*)((char*)vl[bf] + (nc * 8 + mk) * 1024 + lane * 16);
        oacc[nc] = __builtin_amdgcn_mfma_f32_32x32x16_bf16(paf[mk], vf, oacc[nc], 0, 0, 0);
      }
      lacc = __builtin_amdgcn_mfma_f32_32x32x16_bf16(paf[mk], ones, lacc, 0, 0, 0);
    }
    __builtin_amdgcn_s_setprio(0);
  };

  loadKV();      // tile 0 -> regs
  storeKV(0);
  loadKV();      // tile 1 -> regs
  int cur = 0;
  for (int it = 0; it < 16; ++it) {
    __syncthreads();   // buf[cur] staged
    computeTile(cur);
    storeKV(cur ^ 1);  // regs -> other buf (last iter: unused, safe)
    loadKV();          // next tile -> regs (over-read stays in ws, unused)
    cur ^= 1;
  }

  const int b = bh >> 3, h = bh & 7;
  float inv[16];
#pragma unroll
  for (int i = 0; i < 16; ++i) inv[i] = __builtin_amdgcn_rcpf(lacc[i]);
#pragma unroll
  for (int nc = 0; nc < 2; ++nc)
#pragma unroll
    for (int i = 0; i < 16; ++i) {
      int n = q0 + wid * 32 + (i & 3) + 8 * (i >> 2) + 4 * hi;
      ao[((size_t)(b * 2048 + n)) * 512 + h * 64 + nc * 32 + l31] =
          (__bf16)(oacc[nc][i] * inv[i]);
    }
}

extern "C" void kernel_launch(void* const* d_in, const int* in_sizes, int n_in,
                              void* d_out, int out_size, void* d_ws, size_t ws_size,
                              hipStream_t stream) {
  (void)in_sizes; (void)n_in; (void)out_size; (void)ws_size;
  const float* x   = (const float*)d_in[0];
  const float* ctx = (const float*)d_in[1];
  const float* Wq  = (const float*)d_in[3];
  const float* Wkv = (const float*)d_in[4];
  const float* Wo  = (const float*)d_in[5];
  float* out = (float*)d_out;

  __bf16* WqT  = (__bf16*)d_ws;                  // [512][512]
  __bf16* WkvT = WqT + 512 * 512;                // [1024][512]
  __bf16* WoT  = WkvT + 1024 * 512;              // [512][512]
  __bf16* qb   = WoT + 512 * 512;                // [32][2048][64]
  __bf16* kb   = qb + (size_t)32 * 2048 * 64;    // [32][2048][64]
  __bf16* vtb  = kb + (size_t)32 * 2048 * 64;    // [32][64][2048]
  __bf16* aob  = vtb + (size_t)32 * 2048 * 64;   // [8192][512]

  prep_k<<<1024, 256, 0, stream>>>(Wq, Wkv, Wo, WqT, WkvT, WoT);
  qkv_k<<<1536, 256, 0, stream>>>(ctx, WkvT, kb, vtb, x, WqT, qb);
  attn_k<<<512, 256, 0, stream>>>(qb, kb, vtb, aob);
  gemm2_k<<<512, 256, 0, stream>>>(aob, WoT, out);
}

// Round 19
// 129.179 us; speedup vs baseline: 1.3530x; 1.3530x over previous
//
#include <hip/hip_runtime.h>
#include <hip/hip_bf16.h>

typedef __bf16 bf16x8 __attribute__((ext_vector_type(8)));
typedef float f32x4 __attribute__((ext_vector_type(4)));
typedef float f32x16 __attribute__((ext_vector_type(16)));
typedef unsigned int uint2v __attribute__((ext_vector_type(2)));

#define LOG2E 1.44269504088896340736f

static __device__ __forceinline__ unsigned int cvtpk_bf16(float lo, float hi) {
  unsigned int r;
  asm("v_cvt_pk_bf16_f32 %0, %1, %2" : "=v"(r) : "v"(lo), "v"(hi));
  return r;
}

// All three weight transposes in one launch.
__global__ __launch_bounds__(256) void prep_k(
    const float* __restrict__ Wq, const float* __restrict__ Wkv,
    const float* __restrict__ Wo, __bf16* __restrict__ WqT,
    __bf16* __restrict__ WkvT, __bf16* __restrict__ WoT) {
  int id = blockIdx.x;
  const float* in;
  __bf16* out;
  int R, C, bx, by;
  float scale;
  if (id < 256) {
    in = Wq; out = WqT; R = 512; C = 512; scale = 0.125f;
    bx = id & 15; by = id >> 4;
  } else if (id < 768) {
    int i2 = id - 256;
    in = Wkv; out = WkvT; R = 512; C = 1024; scale = 1.0f;
    bx = i2 & 31; by = i2 >> 5;
  } else {
    int i2 = id - 768;
    in = Wo; out = WoT; R = 512; C = 512; scale = 1.0f;
    bx = i2 & 15; by = i2 >> 4;
  }
  __shared__ float tile[32][33];
  int c0 = bx * 32, r0 = by * 32;
  int tx = threadIdx.x & 31, ty = threadIdx.x >> 5;
  for (int i = ty; i < 32; i += 8)
    tile[i][tx] = in[(size_t)(r0 + i) * C + c0 + tx];
  __syncthreads();
  for (int i = ty; i < 32; i += 8)
    out[(size_t)(c0 + i) * R + r0 + tx] = (__bf16)(tile[tx][i] * scale);
}

// GEMM body, BM=128 x BN=64 x BK=64, 4 waves, LDS 48KB (Al 32K + Bl 16K
// double-buffered) -> 3 blocks/CU = 3 independent barrier groups: when one
// block stalls on the staging vmcnt, two others issue MFMA (the phase
// compute ~100-250cy cannot cover ~500cy L2 latency alone — r15's 2-group
// config left the stall exposed). Fragment-granule LDS, reg-staged 2-phase.
// EPI 0: q scatter; EPI 1: gx<8 k scatter, gx>=8 ONE-head vT transpose;
// EPI 2: fp32 row-major [M][512].
template <int EPI, bool AF32>
static __device__ __forceinline__ void gemm_body(
    char* smem, const void* __restrict__ Aptr, const __bf16* __restrict__ Bt,
    void* __restrict__ outp, void* __restrict__ outp2, int id) {
  constexpr int K = 512;
  __bf16* Al = (__bf16*)smem;                    // [2][8192]
  __bf16* Bl = (__bf16*)(smem + 32 * 1024);      // [2][4096]
  const int t = threadIdx.x, lane = t & 63, wid = t >> 6;
  const int lrow = lane & 15, lgrp = lane >> 4;
  const int gy = id & 63, gx = id >> 6;
  const int m0 = gy * 128, n0 = gx * 64;
  const int wr = (wid >> 1) * 64, wc = (wid & 1) * 32;
  f32x4 acc[4][2] = {};
  bf16x8 ar[4], br[2];

  auto loadG = [&](int k0) {
#pragma unroll
    for (int j = 0; j < 4; ++j) {
      int G = j * 256 + t;
      size_t off = (size_t)(m0 + ((G >> 7) << 4) + (G & 15)) * K + k0 +
                   ((G >> 4) & 7) * 8;
      if constexpr (AF32) {
        const float* Af = (const float*)Aptr;
        float4 f0 = *(const float4*)&Af[off];
        float4 f1 = *(const float4*)&Af[off + 4];
        bf16x8 h = {(__bf16)f0.x, (__bf16)f0.y, (__bf16)f0.z, (__bf16)f0.w,
                    (__bf16)f1.x, (__bf16)f1.y, (__bf16)f1.z, (__bf16)f1.w};
        ar[j] = h;
      } else {
        ar[j] = *(const bf16x8*)&((const __bf16*)Aptr)[off];
      }
    }
#pragma unroll
    for (int j = 0; j < 2; ++j) {
      int G = j * 256 + t;
      br[j] = *(const bf16x8*)&Bt[(size_t)(n0 + ((G >> 7) << 4) + (G & 15)) * K +
                                  k0 + ((G >> 4) & 7) * 8];
    }
  };
  auto writeLds = [&](int bf) {
#pragma unroll
    for (int j = 0; j < 4; ++j) *(bf16x8*)&Al[bf * 8192 + (j * 256 + t) * 8] = ar[j];
#pragma unroll
    for (int j = 0; j < 2; ++j) *(bf16x8*)&Bl[bf * 4096 + (j * 256 + t) * 8] = br[j];
  };
  auto mfmaStep = [&](int bf) {
    __builtin_amdgcn_s_setprio(1);
#pragma unroll
    for (int kk = 0; kk < 2; ++kk) {
      bf16x8 af[4], bfr[2];
#pragma unroll
      for (int mi = 0; mi < 4; ++mi)
        af[mi] = *(const bf16x8*)&Al[bf * 8192 + ((wr >> 4) + mi) * 1024 +
                                     kk * 512 + lane * 8];
#pragma unroll
      for (int ni = 0; ni < 2; ++ni)
        bfr[ni] = *(const bf16x8*)&Bl[bf * 4096 + ((wc >> 4) + ni) * 1024 +
                                      kk * 512 + lane * 8];
#pragma unroll
      for (int mi = 0; mi < 4; ++mi)
#pragma unroll
        for (int ni = 0; ni < 2; ++ni)
          acc[mi][ni] = __builtin_amdgcn_mfma_f32_16x16x32_bf16(
              af[mi], bfr[ni], acc[mi][ni], 0, 0, 0);
    }
    __builtin_amdgcn_s_setprio(0);
  };

  const int NIT = K >> 6;  // = 8
  loadG(0);
  writeLds(0);
  int cur = 0;
  for (int it = 0; it < NIT; ++it) {
    __syncthreads();
    if (it + 1 < NIT) loadG((it + 1) << 6);
    mfmaStep(cur);
    if (it + 1 < NIT) writeLds(cur ^ 1);
    cur ^= 1;
  }

  if (EPI == 1 && n0 >= 512) {
    // one v head (hglob = gx-8): transpose 64hd x 128m through Bl scratch
    __syncthreads();  // all waves done reading Bl
    __bf16* scratch = Bl;  // 64*128 bf16 = 16KB (both Bl buffers)
#pragma unroll
    for (int mi = 0; mi < 4; ++mi)
#pragma unroll
      for (int ni = 0; ni < 2; ++ni)
#pragma unroll
        for (int i = 0; i < 4; ++i)
          scratch[(wc + ni * 16 + lrow) * 128 + wr + mi * 16 + lgrp * 4 + i] =
              (__bf16)acc[mi][ni][i];
    __syncthreads();
    const int b = m0 >> 11, mloc = m0 & 2047, hglob = gx - 8;
    int hd = t >> 2, ms = (t & 3) * 32;
    __bf16* dst = (__bf16*)outp2 +
                  ((size_t)(b * 8 + hglob) * 64 + hd) * 2048 + mloc + ms;
    const __bf16* srcT = scratch + hd * 128 + ms;
#pragma unroll
    for (int c2 = 0; c2 < 32; c2 += 8)
      *(bf16x8*)&dst[c2] = *(const bf16x8*)&srcT[c2];
    return;
  }

#pragma unroll
  for (int mi = 0; mi < 4; ++mi)
#pragma unroll
    for (int ni = 0; ni < 2; ++ni)
#pragma unroll
      for (int i = 0; i < 4; ++i) {
        int r = m0 + wr + mi * 16 + lgrp * 4 + i;
        int c = n0 + wc + ni * 16 + lrow;
        float v = acc[mi][ni][i];
        if (EPI == 0) {
          int b = r >> 11, n = r & 2047, h = c >> 6, hd = c & 63;
          ((__bf16*)outp)[((size_t)(b * 8 + h) * 2048 + n) * 64 + hd] = (__bf16)v;
        } else if (EPI == 1) {
          int b = r >> 11, m = r & 2047, h = c >> 6, hd = c & 63;
          ((__bf16*)outp)[((size_t)(b * 8 + h) * 2048 + m) * 64 + hd] = (__bf16)v;
        } else {
          ((float*)outp)[(size_t)r * 512 + c] = v;
        }
      }
}

// Fused QKV projection: blocks [0,1024) = ctx->k,vT (EPI1, N=1024, 16 gx);
// blocks [1024,1536) = x->q (EPI0, N=512, 8 gx). 48KB LDS -> 3 blocks/CU.
__global__ __launch_bounds__(256) void qkv_k(
    const float* __restrict__ ctx, const __bf16* __restrict__ WkvT,
    void* __restrict__ kb, void* __restrict__ vtb,
    const float* __restrict__ x, const __bf16* __restrict__ WqT,
    void* __restrict__ qb) {
  __shared__ __attribute__((aligned(16))) char smem[48 * 1024];
  int id = blockIdx.x;
  if (id < 1024)
    gemm_body<1, true>(smem, ctx, WkvT, kb, vtb, id);
  else
    gemm_body<0, true>(smem, x, WqT, qb, nullptr, id - 1024);
}

// Output projection: aob (bf16) @ WoT -> fp32 out. 512 blocks, 3/CU.
__global__ __launch_bounds__(256) void gemm2_k(
    const __bf16* __restrict__ A, const __bf16* __restrict__ Bt,
    float* __restrict__ out) {
  __shared__ __attribute__((aligned(16))) char smem[48 * 1024];
  gemm_body<2, false>(smem, A, Bt, out, nullptr, blockIdx.x);
}

// Flash attention (round-13 version, measured 53.5us): 32x32x16 MFMA,
// in-register P, fixed-shift softmax, KVBLK=128 (16 phases), fragment-
// granule LDS, 2-phase dbuf, reg-staged, unconditional staging.
__global__ __launch_bounds__(256, 2) void attn_k(
    const __bf16* __restrict__ q, const __bf16* __restrict__ k,
    const __bf16* __restrict__ vt, __bf16* __restrict__ ao) {
  const int id = blockIdx.x;
  const int bh = id & 31;  // id%8 == bh%8 -> one bh's blocks share an XCD
  const int q0 = (id >> 5) * 128;
  const int t = threadIdx.x, wid = t >> 6, lane = t & 63;
  const int l31 = lane & 31, hi = lane >> 5;

  __shared__ __attribute__((aligned(16))) __bf16 kl[2][8192];  // 128m x 64hd
  __shared__ __attribute__((aligned(16))) __bf16 vl[2][8192];  // 64hd x 128m

  const size_t qrow = (size_t)bh * 2048 + q0 + wid * 32 + l31;
  bf16x8 qf[4];
#pragma unroll
  for (int kc = 0; kc < 4; ++kc)
    qf[kc] = *(const bf16x8*)&q[qrow * 64 + kc * 16 + hi * 8];

  const __bf16* kp = k + (size_t)bh * 2048 * 64 + (size_t)l31 * 64 + wid * 16 + hi * 8;
  const __bf16* vp = vt + (size_t)bh * 64 * 2048 + (size_t)l31 * 2048 + wid * 16 + hi * 8;
  const int sg = wid * 1024 + lane * 16;  // LDS byte base, +j*4096

  bf16x8 ones;
#pragma unroll
  for (int e = 0; e < 8; ++e) ones[e] = (__bf16)1.0f;

  f32x16 oacc[2] = {};
  f32x16 lacc = {};
  const float ncl = -8.0f * LOG2E;

  bf16x8 kr[4], vr[4];
  auto loadKV = [&]() {
    kr[0] = *(const bf16x8*)kp;
    kr[1] = *(const bf16x8*)(kp + 2048);
    kr[2] = *(const bf16x8*)(kp + 4096);
    kr[3] = *(const bf16x8*)(kp + 6144);
    vr[0] = *(const bf16x8*)vp;
    vr[1] = *(const bf16x8*)(vp + 64);
    vr[2] = *(const bf16x8*)(vp + 65536);
    vr[3] = *(const bf16x8*)(vp + 65600);
    kp += 8192;
    vp += 128;
  };
  auto storeKV = [&](int bf) {
#pragma unroll
    for (int j = 0; j < 4; ++j) {
      *(bf16x8*)((char*)kl[bf] + sg + j * 4096) = kr[j];
      *(bf16x8*)((char*)vl[bf] + sg + j * 4096) = vr[j];
    }
  };
  auto computeTile = [&](int bf) {
    f32x16 sacc[4] = {};
    __builtin_amdgcn_s_setprio(1);
#pragma unroll
    for (int kc = 0; kc < 4; ++kc)
#pragma unroll
      for (int mc = 0; mc < 4; ++mc) {
        bf16x8 ak = *(const bf16x8*)((char*)kl[bf] + (mc * 4 + kc) * 1024 + lane * 16);
        sacc[mc] = __builtin_amdgcn_mfma_f32_32x32x16_bf16(ak, qf[kc], sacc[mc], 0, 0, 0);
      }
    __builtin_amdgcn_s_setprio(0);

#pragma unroll
    for (int mc = 0; mc < 4; ++mc)
#pragma unroll
      for (int r = 0; r < 16; ++r)
        sacc[mc][r] =
            __builtin_amdgcn_exp2f(__builtin_fmaf(sacc[mc][r], LOG2E, ncl));

    bf16x8 paf[8];
#pragma unroll
    for (int mc = 0; mc < 4; ++mc)
#pragma unroll
      for (int w = 0; w < 2; ++w) {
        int b0 = w * 8;
        unsigned int dwA = cvtpk_bf16(sacc[mc][b0 + 0], sacc[mc][b0 + 1]);
        unsigned int dwB = cvtpk_bf16(sacc[mc][b0 + 2], sacc[mc][b0 + 3]);
        unsigned int dwC = cvtpk_bf16(sacc[mc][b0 + 4], sacc[mc][b0 + 5]);
        unsigned int dwD = cvtpk_bf16(sacc[mc][b0 + 6], sacc[mc][b0 + 7]);
        uint2v r0 = __builtin_amdgcn_permlane32_swap(dwA, dwC, false, false);
        uint2v r1 = __builtin_amdgcn_permlane32_swap(dwB, dwD, false, false);
        union { unsigned int u[4]; bf16x8 v; } f;
        f.u[0] = r0[0];
        f.u[1] = r1[0];
        f.u[2] = r0[1];
        f.u[3] = r1[1];
        paf[mc * 2 + w] = f.v;
      }

    __builtin_amdgcn_s_setprio(1);
#pragma unroll
    for (int mk = 0; mk < 8; ++mk) {
#pragma unroll
      for (int nc = 0; nc < 2; ++nc) {
        bf16x8 vf = *(const bf16x8*)((char*)vl[bf] + (nc * 8 + mk) * 1024 + lane * 16);
        oacc[nc] = __builtin_amdgcn_mfma_f32_32x32x16_bf16(paf[mk], vf, oacc[nc], 0, 0, 0);
      }
      lacc = __builtin_amdgcn_mfma_f32_32x32x16_bf16(paf[mk], ones, lacc, 0, 0, 0);
    }
    __builtin_amdgcn_s_setprio(0);
  };

  loadKV();      // tile 0 -> regs
  storeKV(0);
  loadKV();      // tile 1 -> regs
  int cur = 0;
  for (int it = 0; it < 16; ++it) {
    __syncthreads();   // buf[cur] staged
    computeTile(cur);
    storeKV(cur ^ 1);  // regs -> other buf (last iter: unused, safe)
    loadKV();          // next tile -> regs (over-read stays in ws, unused)
    cur ^= 1;
  }

  const int b = bh >> 3, h = bh & 7;
  float inv[16];
#pragma unroll
  for (int i = 0; i < 16; ++i) inv[i] = __builtin_amdgcn_rcpf(lacc[i]);
#pragma unroll
  for (int nc = 0; nc < 2; ++nc)
#pragma unroll
    for (int i = 0; i < 16; ++i) {
      int n = q0 + wid * 32 + (i & 3) + 8 * (i >> 2) + 4 * hi;
      ao[((size_t)(b * 2048 + n)) * 512 + h * 64 + nc * 32 + l31] =
          (__bf16)(oacc[nc][i] * inv[i]);
    }
}

extern "C" void kernel_launch(void* const* d_in, const int* in_sizes, int n_in,
                              void* d_out, int out_size, void* d_ws, size_t ws_size,
                              hipStream_t stream) {
  (void)in_sizes; (void)n_in; (void)out_size; (void)ws_size;
  const float* x   = (const float*)d_in[0];
  const float* ctx = (const float*)d_in[1];
  const float* Wq  = (const float*)d_in[3];
  const float* Wkv = (const float*)d_in[4];
  const float* Wo  = (const float*)d_in[5];
  float* out = (float*)d_out;

  __bf16* WqT  = (__bf16*)d_ws;                  // [512][512]
  __bf16* WkvT = WqT + 512 * 512;                // [1024][512]
  __bf16* WoT  = WkvT + 1024 * 512;              // [512][512]
  __bf16* qb   = WoT + 512 * 512;                // [32][2048][64]
  __bf16* kb   = qb + (size_t)32 * 2048 * 64;    // [32][2048][64]
  __bf16* vtb  = kb + (size_t)32 * 2048 * 64;    // [32][64][2048]
  __bf16* aob  = vtb + (size_t)32 * 2048 * 64;   // [8192][512]

  prep_k<<<1024, 256, 0, stream>>>(Wq, Wkv, Wo, WqT, WkvT, WoT);
  qkv_k<<<1536, 256, 0, stream>>>(ctx, WkvT, kb, vtb, x, WqT, qb);
  attn_k<<<512, 256, 0, stream>>>(qb, kb, vtb, aob);
  gemm2_k<<<512, 256, 0, stream>>>(aob, WoT, out);
}

// Round 20
// 111.877 us; speedup vs baseline: 1.5622x; 1.1547x over previous
//
#include <hip/hip_runtime.h>
#include <hip/hip_bf16.h>

typedef __bf16 bf16x8 __attribute__((ext_vector_type(8)));
typedef float f32x4 __attribute__((ext_vector_type(4)));
typedef float f32x16 __attribute__((ext_vector_type(16)));
typedef unsigned int uint2v __attribute__((ext_vector_type(2)));

#define LOG2E 1.44269504088896340736f

static __device__ __forceinline__ unsigned int cvtpk_bf16(float lo, float hi) {
  unsigned int r;
  asm("v_cvt_pk_bf16_f32 %0, %1, %2" : "=v"(r) : "v"(lo), "v"(hi));
  return r;
}

// All three weight transposes in one launch.
__global__ __launch_bounds__(256) void prep_k(
    const float* __restrict__ Wq, const float* __restrict__ Wkv,
    const float* __restrict__ Wo, __bf16* __restrict__ WqT,
    __bf16* __restrict__ WkvT, __bf16* __restrict__ WoT) {
  int id = blockIdx.x;
  const float* in;
  __bf16* out;
  int R, C, bx, by;
  float scale;
  if (id < 256) {
    in = Wq; out = WqT; R = 512; C = 512; scale = 0.125f;
    bx = id & 15; by = id >> 4;
  } else if (id < 768) {
    int i2 = id - 256;
    in = Wkv; out = WkvT; R = 512; C = 1024; scale = 1.0f;
    bx = i2 & 31; by = i2 >> 5;
  } else {
    int i2 = id - 768;
    in = Wo; out = WoT; R = 512; C = 512; scale = 1.0f;
    bx = i2 & 15; by = i2 >> 4;
  }
  __shared__ float tile[32][33];
  int c0 = bx * 32, r0 = by * 32;
  int tx = threadIdx.x & 31, ty = threadIdx.x >> 5;
  for (int i = ty; i < 32; i += 8)
    tile[i][tx] = in[(size_t)(r0 + i) * C + c0 + tx];
  __syncthreads();
  for (int i = ty; i < 32; i += 8)
    out[(size_t)(c0 + i) * R + r0 + tx] = (__bf16)(tile[tx][i] * scale);
}

// GEMM body (r15 structure, measured best): BM=128 x BN=128 x BK=64,
// fragment-granule LDS (0 conflicts), dbuf, reg-staged 2-phase, 64KB LDS
// (Al 32K + Bl 32K) -> 2 blocks/CU. Wide BN = fewer A-panel refetches and
// 32 MFMA/phase/wave (r19 showed BN=64 doubles A-fetch and regresses).
// EPI 0: q scatter; EPI 1: n0<512 k scatter, n0>=512 two-head vT transpose;
// EPI 2: fp32 row-major [M][N].
template <int EPI, int BN, bool AF32>
static __device__ __forceinline__ void gemm_body(
    char* smem, const void* __restrict__ Aptr, const __bf16* __restrict__ Bt,
    void* __restrict__ outp, void* __restrict__ outp2, int M, int N, int K,
    int id) {
  constexpr int NI = BN / 32;
  constexpr int BJ = BN / 32;
  __bf16* Al = (__bf16*)smem;                    // [2][128*64]
  __bf16* Bl = (__bf16*)(smem + 32 * 1024);      // [2][BN*64]
  const int t = threadIdx.x, lane = t & 63, wid = t >> 6;
  const int lrow = lane & 15, lgrp = lane >> 4;
  const int gy = id & 63, gx = id >> 6;
  const int m0 = gy * 128, n0 = gx * BN;
  const int wr = (wid >> 1) * 64, wc = (wid & 1) * (BN / 2);
  f32x4 acc[4][NI] = {};
  bf16x8 ar[4], br[BJ];

  auto loadG = [&](int k0) {
#pragma unroll
    for (int j = 0; j < 4; ++j) {
      int G = j * 256 + t;
      size_t off = (size_t)(m0 + ((G >> 7) << 4) + (G & 15)) * K + k0 +
                   ((G >> 4) & 7) * 8;
      if constexpr (AF32) {
        const float* Af = (const float*)Aptr;
        float4 f0 = *(const float4*)&Af[off];
        float4 f1 = *(const float4*)&Af[off + 4];
        bf16x8 h = {(__bf16)f0.x, (__bf16)f0.y, (__bf16)f0.z, (__bf16)f0.w,
                    (__bf16)f1.x, (__bf16)f1.y, (__bf16)f1.z, (__bf16)f1.w};
        ar[j] = h;
      } else {
        ar[j] = *(const bf16x8*)&((const __bf16*)Aptr)[off];
      }
    }
#pragma unroll
    for (int j = 0; j < BJ; ++j) {
      int G = j * 256 + t;
      br[j] = *(const bf16x8*)&Bt[(size_t)(n0 + ((G >> 7) << 4) + (G & 15)) * K +
                                  k0 + ((G >> 4) & 7) * 8];
    }
  };
  auto writeLds = [&](int bf) {
#pragma unroll
    for (int j = 0; j < 4; ++j)
      *(bf16x8*)&Al[bf * 8192 + (j * 256 + t) * 8] = ar[j];
#pragma unroll
    for (int j = 0; j < BJ; ++j)
      *(bf16x8*)&Bl[bf * BN * 64 + (j * 256 + t) * 8] = br[j];
  };
  auto mfmaStep = [&](int bf) {
    __builtin_amdgcn_s_setprio(1);
#pragma unroll
    for (int kk = 0; kk < 2; ++kk) {
      bf16x8 af[4], bfr[NI];
#pragma unroll
      for (int mi = 0; mi < 4; ++mi)
        af[mi] = *(const bf16x8*)&Al[bf * 8192 + ((wr >> 4) + mi) * 1024 +
                                     kk * 512 + lane * 8];
#pragma unroll
      for (int ni = 0; ni < NI; ++ni)
        bfr[ni] = *(const bf16x8*)&Bl[bf * BN * 64 + ((wc >> 4) + ni) * 1024 +
                                      kk * 512 + lane * 8];
#pragma unroll
      for (int mi = 0; mi < 4; ++mi)
#pragma unroll
        for (int ni = 0; ni < NI; ++ni)
          acc[mi][ni] = __builtin_amdgcn_mfma_f32_16x16x32_bf16(
              af[mi], bfr[ni], acc[mi][ni], 0, 0, 0);
    }
    __builtin_amdgcn_s_setprio(0);
  };

  const int NIT = K >> 6;  // = 8
  loadG(0);
  writeLds(0);
  int cur = 0;
  for (int it = 0; it < NIT; ++it) {
    __syncthreads();
    if (it + 1 < NIT) loadG((it + 1) << 6);
    mfmaStep(cur);
    if (it + 1 < NIT) writeLds(cur ^ 1);
    cur ^= 1;
  }

  if (EPI == 1 && n0 >= 512) {
    // V blocks: 2 heads/block, transpose 64hd x 128m per head through Bl.
    const int b = m0 >> 11, mloc = m0 & 2047;
#pragma unroll 1
    for (int hh = 0; hh < 2; ++hh) {
      __syncthreads();
      if ((wid & 1) == hh) {
#pragma unroll
        for (int mi = 0; mi < 4; ++mi)
#pragma unroll
          for (int ni = 0; ni < NI; ++ni)
#pragma unroll
            for (int i = 0; i < 4; ++i)
              Bl[(ni * 16 + lrow) * 128 + (wr + mi * 16 + lgrp * 4 + i)] =
                  (__bf16)acc[mi][ni][i];
      }
      __syncthreads();
      int hglob = ((n0 - 512) >> 6) + hh;
      int hd = t >> 2, ms = (t & 3) * 32;
      __bf16* dst = (__bf16*)outp2 +
                    ((size_t)(b * 8 + hglob) * 64 + hd) * 2048 + mloc + ms;
      const __bf16* srcT = Bl + hd * 128 + ms;
#pragma unroll
      for (int c2 = 0; c2 < 32; c2 += 8)
        *(bf16x8*)&dst[c2] = *(const bf16x8*)&srcT[c2];
    }
    return;
  }

#pragma unroll
  for (int mi = 0; mi < 4; ++mi)
#pragma unroll
    for (int ni = 0; ni < NI; ++ni)
#pragma unroll
      for (int i = 0; i < 4; ++i) {
        int r = m0 + wr + mi * 16 + lgrp * 4 + i;
        int c = n0 + wc + ni * 16 + lrow;
        float v = acc[mi][ni][i];
        if (EPI == 0) {
          int b = r >> 11, n = r & 2047, h = c >> 6, hd = c & 63;
          ((__bf16*)outp)[((size_t)(b * 8 + h) * 2048 + n) * 64 + hd] = (__bf16)v;
        } else if (EPI == 1) {
          int b = r >> 11, m = r & 2047, h = c >> 6, hd = c & 63;
          ((__bf16*)outp)[((size_t)(b * 8 + h) * 2048 + m) * 64 + hd] = (__bf16)v;
        } else {
          ((float*)outp)[(size_t)r * N + c] = v;
        }
      }
}

// Fused QKV projection: blocks [0,512) = ctx->k,vT (EPI1, N=1024, 8 gx);
// blocks [512,768) = x->q (EPI0, N=512, 4 gx). 64KB LDS -> 2 blocks/CU.
__global__ __launch_bounds__(256) void qkv_k(
    const float* __restrict__ ctx, const __bf16* __restrict__ WkvT,
    void* __restrict__ kb, void* __restrict__ vtb,
    const float* __restrict__ x, const __bf16* __restrict__ WqT,
    void* __restrict__ qb) {
  __shared__ __attribute__((aligned(16))) char smem[64 * 1024];
  int id = blockIdx.x;
  if (id < 512)
    gemm_body<1, 128, true>(smem, ctx, WkvT, kb, vtb, 8192, 1024, 512, id);
  else
    gemm_body<0, 128, true>(smem, x, WqT, qb, nullptr, 8192, 512, 512, id - 512);
}

// Output projection: aob (bf16) @ WoT -> fp32 out. 256 blocks (BN=128).
__global__ __launch_bounds__(256) void gemm2_k(
    const __bf16* __restrict__ A, const __bf16* __restrict__ Bt,
    float* __restrict__ out) {
  __shared__ __attribute__((aligned(16))) char smem[64 * 1024];
  gemm_body<2, 128, false>(smem, A, Bt, out, nullptr, 8192, 512, 512,
                           blockIdx.x);
}

// Flash attention (round-13 version, measured 53.5us): 32x32x16 MFMA,
// in-register P, fixed-shift softmax, KVBLK=128 (16 phases), fragment-
// granule LDS, 2-phase dbuf, reg-staged, unconditional staging.
__global__ __launch_bounds__(256, 2) void attn_k(
    const __bf16* __restrict__ q, const __bf16* __restrict__ k,
    const __bf16* __restrict__ vt, __bf16* __restrict__ ao) {
  const int id = blockIdx.x;
  const int bh = id & 31;  // id%8 == bh%8 -> one bh's blocks share an XCD
  const int q0 = (id >> 5) * 128;
  const int t = threadIdx.x, wid = t >> 6, lane = t & 63;
  const int l31 = lane & 31, hi = lane >> 5;

  __shared__ __attribute__((aligned(16))) __bf16 kl[2][8192];  // 128m x 64hd
  __shared__ __attribute__((aligned(16))) __bf16 vl[2][8192];  // 64hd x 128m

  const size_t qrow = (size_t)bh * 2048 + q0 + wid * 32 + l31;
  bf16x8 qf[4];
#pragma unroll
  for (int kc = 0; kc < 4; ++kc)
    qf[kc] = *(const bf16x8*)&q[qrow * 64 + kc * 16 + hi * 8];

  const __bf16* kp = k + (size_t)bh * 2048 * 64 + (size_t)l31 * 64 + wid * 16 + hi * 8;
  const __bf16* vp = vt + (size_t)bh * 64 * 2048 + (size_t)l31 * 2048 + wid * 16 + hi * 8;
  const int sg = wid * 1024 + lane * 16;  // LDS byte base, +j*4096

  bf16x8 ones;
#pragma unroll
  for (int e = 0; e < 8; ++e) ones[e] = (__bf16)1.0f;

  f32x16 oacc[2] = {};
  f32x16 lacc = {};
  const float ncl = -8.0f * LOG2E;

  bf16x8 kr[4], vr[4];
  auto loadKV = [&]() {
    kr[0] = *(const bf16x8*)kp;
    kr[1] = *(const bf16x8*)(kp + 2048);
    kr[2] = *(const bf16x8*)(kp + 4096);
    kr[3] = *(const bf16x8*)(kp + 6144);
    vr[0] = *(const bf16x8*)vp;
    vr[1] = *(const bf16x8*)(vp + 64);
    vr[2] = *(const bf16x8*)(vp + 65536);
    vr[3] = *(const bf16x8*)(vp + 65600);
    kp += 8192;
    vp += 128;
  };
  auto storeKV = [&](int bf) {
#pragma unroll
    for (int j = 0; j < 4; ++j) {
      *(bf16x8*)((char*)kl[bf] + sg + j * 4096) = kr[j];
      *(bf16x8*)((char*)vl[bf] + sg + j * 4096) = vr[j];
    }
  };
  auto computeTile = [&](int bf) {
    f32x16 sacc[4] = {};
    __builtin_amdgcn_s_setprio(1);
#pragma unroll
    for (int kc = 0; kc < 4; ++kc)
#pragma unroll
      for (int mc = 0; mc < 4; ++mc) {
        bf16x8 ak = *(const bf16x8*)((char*)kl[bf] + (mc * 4 + kc) * 1024 + lane * 16);
        sacc[mc] = __builtin_amdgcn_mfma_f32_32x32x16_bf16(ak, qf[kc], sacc[mc], 0, 0, 0);
      }
    __builtin_amdgcn_s_setprio(0);

#pragma unroll
    for (int mc = 0; mc < 4; ++mc)
#pragma unroll
      for (int r = 0; r < 16; ++r)
        sacc[mc][r] =
            __builtin_amdgcn_exp2f(__builtin_fmaf(sacc[mc][r], LOG2E, ncl));

    bf16x8 paf[8];
#pragma unroll
    for (int mc = 0; mc < 4; ++mc)
#pragma unroll
      for (int w = 0; w < 2; ++w) {
        int b0 = w * 8;
        unsigned int dwA = cvtpk_bf16(sacc[mc][b0 + 0], sacc[mc][b0 + 1]);
        unsigned int dwB = cvtpk_bf16(sacc[mc][b0 + 2], sacc[mc][b0 + 3]);
        unsigned int dwC = cvtpk_bf16(sacc[mc][b0 + 4], sacc[mc][b0 + 5]);
        unsigned int dwD = cvtpk_bf16(sacc[mc][b0 + 6], sacc[mc][b0 + 7]);
        uint2v r0 = __builtin_amdgcn_permlane32_swap(dwA, dwC, false, false);
        uint2v r1 = __builtin_amdgcn_permlane32_swap(dwB, dwD, false, false);
        union { unsigned int u[4]; bf16x8 v; } f;
        f.u[0] = r0[0];
        f.u[1] = r1[0];
        f.u[2] = r0[1];
        f.u[3] = r1[1];
        paf[mc * 2 + w] = f.v;
      }

    __builtin_amdgcn_s_setprio(1);
#pragma unroll
    for (int mk = 0; mk < 8; ++mk) {
#pragma unroll
      for (int nc = 0; nc < 2; ++nc) {
        bf16x8 vf = *(const bf16x8*)((char*)vl[bf] + (nc * 8 + mk) * 1024 + lane * 16);
        oacc[nc] = __builtin_amdgcn_mfma_f32_32x32x16_bf16(paf[mk], vf, oacc[nc], 0, 0, 0);
      }
      lacc = __builtin_amdgcn_mfma_f32_32x32x16_bf16(paf[mk], ones, lacc, 0, 0, 0);
    }
    __builtin_amdgcn_s_setprio(0);
  };

  loadKV();      // tile 0 -> regs
  storeKV(0);
  loadKV();      // tile 1 -> regs
  int cur = 0;
  for (int it = 0; it < 16; ++it) {
    __syncthreads();   // buf[cur] staged
    computeTile(cur);
    storeKV(cur ^ 1);  // regs -> other buf (last iter: unused, safe)
    loadKV();          // next tile -> regs (over-read stays in ws, unused)
    cur ^= 1;
  }

  const int b = bh >> 3, h = bh & 7;
  float inv[16];
#pragma unroll
  for (int i = 0; i < 16; ++i) inv[i] = __builtin_amdgcn_rcpf(lacc[i]);
#pragma unroll
  for (int nc = 0; nc < 2; ++nc)
#pragma unroll
    for (int i = 0; i < 16; ++i) {
      int n = q0 + wid * 32 + (i & 3) + 8 * (i >> 2) + 4 * hi;
      ao[((size_t)(b * 2048 + n)) * 512 + h * 64 + nc * 32 + l31] =
          (__bf16)(oacc[nc][i] * inv[i]);
    }
}

extern "C" void kernel_launch(void* const* d_in, const int* in_sizes, int n_in,
                              void* d_out, int out_size, void* d_ws, size_t ws_size,
                              hipStream_t stream) {
  (void)in_sizes; (void)n_in; (void)out_size; (void)ws_size;
  const float* x   = (const float*)d_in[0];
  const float* ctx = (const float*)d_in[1];
  const float* Wq  = (const float*)d_in[3];
  const float* Wkv = (const float*)d_in[4];
  const float* Wo  = (const float*)d_in[5];
  float* out = (float*)d_out;

  __bf16* WqT  = (__bf16*)d_ws;                  // [512][512]
  __bf16* WkvT = WqT + 512 * 512;                // [1024][512]
  __bf16* WoT  = WkvT + 1024 * 512;              // [512][512]
  __bf16* qb   = WoT + 512 * 512;                // [32][2048][64]
  __bf16* kb   = qb + (size_t)32 * 2048 * 64;    // [32][2048][64]
  __bf16* vtb  = kb + (size_t)32 * 2048 * 64;    // [32][64][2048]
  __bf16* aob  = vtb + (size_t)32 * 2048 * 64;   // [8192][512]

  prep_k<<<1024, 256, 0, stream>>>(Wq, Wkv, Wo, WqT, WkvT, WoT);
  qkv_k<<<768, 256, 0, stream>>>(ctx, WkvT, kb, vtb, x, WqT, qb);
  attn_k<<<512, 256, 0, stream>>>(qb, kb, vtb, aob);
  gemm2_k<<<256, 256, 0, stream>>>(aob, WoT, out);
}